// Round 1
// baseline (29339.191 us; speedup 1.0000x reference)
//
#include <hip/hip_runtime.h>

#define HH 500
#define G4 2000
#define NSEQ 2304
#define NGOALS 256
#define NHYPS 2048
#define LSEQ 128
#define NVOCAB 1000
#define NEG_SLOPE 0.01f

__device__ __forceinline__ float sigm(float x) { return 1.0f / (1.0f + expf(-x)); }

// Generic C[M,N] = act(A[M,K] @ B[N,K]^T + bias[n] (+bias2[n]))
// act: 0=none, 1=leaky relu
__global__ void gemm_at_bt(const float* __restrict__ A, const float* __restrict__ B,
                           const float* __restrict__ bias, const float* __restrict__ bias2,
                           float* __restrict__ C, int M, int N, int K, int act)
{
    __shared__ float as[32][17];
    __shared__ float bs[32][17];
    int tid = threadIdx.x;
    int tx = tid & 15, ty = tid >> 4;
    int m0 = blockIdx.y * 32, n0 = blockIdx.x * 32;
    float acc[2][2] = {};
    for (int k0 = 0; k0 < K; k0 += 16) {
        #pragma unroll
        for (int i = 0; i < 2; ++i) {
            int idx = i * 256 + tid;
            int r = idx >> 4, k = idx & 15;
            int gm = m0 + r, gk = k0 + k;
            as[r][k] = (gm < M && gk < K) ? A[gm * K + gk] : 0.0f;
            int gn = n0 + r;
            bs[r][k] = (gn < N && gk < K) ? B[gn * K + gk] : 0.0f;
        }
        __syncthreads();
        #pragma unroll
        for (int kk = 0; kk < 16; ++kk) {
            float a0 = as[ty][kk], a1 = as[ty + 16][kk];
            float b0 = bs[tx][kk], b1 = bs[tx + 16][kk];
            acc[0][0] += a0 * b0; acc[0][1] += a0 * b1;
            acc[1][0] += a1 * b0; acc[1][1] += a1 * b1;
        }
        __syncthreads();
    }
    #pragma unroll
    for (int i = 0; i < 2; ++i) {
        int m = m0 + ty + i * 16;
        if (m >= M) continue;
        #pragma unroll
        for (int j = 0; j < 2; ++j) {
            int n = n0 + tx + j * 16;
            if (n >= N) continue;
            float v = acc[i][j];
            if (bias)  v += bias[n];
            if (bias2) v += bias2[n];
            if (act == 1) v = (v >= 0.0f) ? v : NEG_SLOPE * v;
            C[m * N + n] = v;
        }
    }
}

// One LSTM timestep, fused: gates = T[token] + h_in @ Whh^T; pointwise update.
// Tile: 32 n x 32 u (each u has 4 gates -> 128 effective columns), K-chunk 16.
// Each thread: 2 n x 2 u x 4 gates = 16 accumulators.
__global__ void lstm_step(const float* __restrict__ T,
                          const int* __restrict__ goals, const int* __restrict__ hyps,
                          const float* __restrict__ Whh,
                          const float* __restrict__ hin, float* __restrict__ hout,
                          float* __restrict__ c, int t)
{
    __shared__ float hs[32][17];    // [n][k]
    __shared__ float wss[128][17];  // row = g*32 + u, [k]
    int tid = threadIdx.x;
    int tx = tid & 15, ty = tid >> 4;
    int u0 = blockIdx.x * 32;  // 16 tiles cover 500 (with tail)
    int n0 = blockIdx.y * 32;  // 72 tiles cover 2304 exactly
    float acc[2][2][4] = {};

    for (int k0 = 0; k0 < HH; k0 += 16) {
        #pragma unroll
        for (int i = 0; i < 2; ++i) {
            int idx = i * 256 + tid;
            int r = idx >> 4, k = idx & 15;
            int gk = k0 + k;
            hs[r][k] = (gk < HH) ? hin[(n0 + r) * HH + gk] : 0.0f;
        }
        #pragma unroll
        for (int i = 0; i < 8; ++i) {
            int idx = i * 256 + tid;
            int r = idx >> 4, k = idx & 15;
            int g = r >> 5, u = r & 31;
            int gk = k0 + k;
            wss[r][k] = (u0 + u < HH && gk < HH) ? Whh[(g * HH + u0 + u) * HH + gk] : 0.0f;
        }
        __syncthreads();
        #pragma unroll
        for (int kk = 0; kk < 16; ++kk) {
            float hv0 = hs[ty][kk], hv1 = hs[ty + 16][kk];
            #pragma unroll
            for (int g = 0; g < 4; ++g) {
                float w0 = wss[g * 32 + tx][kk], w1 = wss[g * 32 + tx + 16][kk];
                acc[0][0][g] += hv0 * w0; acc[0][1][g] += hv0 * w1;
                acc[1][0][g] += hv1 * w0; acc[1][1][g] += hv1 * w1;
            }
        }
        __syncthreads();
    }

    #pragma unroll
    for (int i = 0; i < 2; ++i) {
        int n = n0 + ty + i * 16;
        int tok = (n < NGOALS) ? goals[n * LSEQ + t] : hyps[(n - NGOALS) * LSEQ + t];
        const float* Trow = T + tok * G4;
        #pragma unroll
        for (int j = 0; j < 2; ++j) {
            int u = u0 + tx + j * 16;
            if (u >= HH) continue;
            float gi = acc[i][j][0] + Trow[u];
            float gf = acc[i][j][1] + Trow[HH + u];
            float gg = acc[i][j][2] + Trow[2 * HH + u];
            float go = acc[i][j][3] + Trow[3 * HH + u];
            float si = sigm(gi), sf = sigm(gf), so = sigm(go);
            float cv = c[n * HH + u];
            cv = sf * cv + si * tanhf(gg);
            c[n * HH + u] = cv;
            hout[n * HH + u] = so * tanhf(cv);
        }
    }
}

__global__ void segsum(const float* __restrict__ hfin, const int* __restrict__ segid,
                       float* __restrict__ hyp_sum)
{
    int row = blockIdx.y;                       // hyp index 0..2047
    int u = blockIdx.x * 256 + threadIdx.x;
    if (u >= HH) return;
    int b = segid[row];
    atomicAdd(&hyp_sum[b * HH + u], hfin[(NGOALS + row) * HH + u]);
}

__global__ void concat_k(const float* __restrict__ hfin, const float* __restrict__ hyp_sum,
                         float* __restrict__ xcat)
{
    int r = blockIdx.y;
    int k = blockIdx.x * 256 + threadIdx.x;
    if (k >= 2 * HH) return;
    xcat[r * 2 * HH + k] = (k < HH) ? hfin[r * HH + k] : hyp_sum[r * HH + (k - HH)];
}

__global__ void rownorm(const float* __restrict__ X, float* __restrict__ out)
{
    __shared__ float red[256];
    int r = blockIdx.x;
    int tid = threadIdx.x;
    float v0 = (tid < HH) ? X[r * HH + tid] : 0.0f;
    float v1 = (tid + 256 < HH) ? X[r * HH + tid + 256] : 0.0f;
    red[tid] = v0 * v0 + v1 * v1;
    __syncthreads();
    for (int st = 128; st > 0; st >>= 1) {
        if (tid < st) red[tid] += red[tid + st];
        __syncthreads();
    }
    float nrm = fmaxf(sqrtf(red[0]), 1e-12f);
    if (tid < HH) out[r * HH + tid] = v0 / nrm;
    if (tid + 256 < HH) out[r * HH + tid + 256] = v1 / nrm;
}

extern "C" void kernel_launch(void* const* d_in, const int* in_sizes, int n_in,
                              void* d_out, int out_size, void* d_ws, size_t ws_size,
                              hipStream_t stream)
{
    const int*   goals = (const int*)d_in[0];
    const int*   hyps  = (const int*)d_in[1];
    const int*   segid = (const int*)d_in[2];
    const float* emb   = (const float*)d_in[3];
    const float* Wih   = (const float*)d_in[4];
    const float* Whh   = (const float*)d_in[5];
    const float* bih   = (const float*)d_in[6];
    const float* bhh   = (const float*)d_in[7];
    const float* W1    = (const float*)d_in[8];
    const float* b1    = (const float*)d_in[9];
    const float* W2    = (const float*)d_in[10];
    const float* b2    = (const float*)d_in[11];
    const float* Wf    = (const float*)d_in[12];
    const float* bf    = (const float*)d_in[13];
    float* out = (float*)d_out;

    float* ws   = (float*)d_ws;
    float* T    = ws;                 // 1000*2000 = 2,000,000
    float* h0   = ws + 2000000;       // 2304*500 = 1,152,000
    float* h1   = ws + 3152000;       // 1,152,000
    float* c    = ws + 4304000;       // 1,152,000
    float* hsum = ws + 5456000;       // 256*500 = 128,000
    float* xcat = ws + 5584000;       // 256*1000 = 256,000
    float* x1   = ws + 5840000;       // 128,000
    float* x2   = ws + 5968000;       // 128,000

    // Token-gate table: T = emb @ Wih^T + bih + bhh   [1000 x 2000]
    gemm_at_bt<<<dim3((G4 + 31) / 32, (NVOCAB + 31) / 32), 256, 0, stream>>>(
        emb, Wih, bih, bhh, T, NVOCAB, G4, HH, 0);

    hipMemsetAsync(h0,   0, 1152000 * sizeof(float), stream);
    hipMemsetAsync(c,    0, 1152000 * sizeof(float), stream);
    hipMemsetAsync(hsum, 0,  128000 * sizeof(float), stream);

    float* hb[2] = { h0, h1 };
    for (int t = 0; t < LSEQ; ++t) {
        lstm_step<<<dim3(16, NSEQ / 32), 256, 0, stream>>>(
            T, goals, hyps, Whh, hb[t & 1], hb[(t + 1) & 1], c, t);
    }
    float* hfin = h0;  // 128 steps -> final lands back in h0

    segsum<<<dim3(2, NHYPS), 256, 0, stream>>>(hfin, segid, hsum);
    concat_k<<<dim3(4, NGOALS), 256, 0, stream>>>(hfin, hsum, xcat);

    gemm_at_bt<<<dim3(16, 8), 256, 0, stream>>>(xcat, W1, b1, nullptr, x1, NGOALS, HH, 2 * HH, 1);
    gemm_at_bt<<<dim3(16, 8), 256, 0, stream>>>(x1,   W2, b2, nullptr, x2, NGOALS, HH, HH, 1);
    gemm_at_bt<<<dim3(16, 8), 256, 0, stream>>>(x2,   Wf, bf, nullptr, xcat, NGOALS, HH, HH, 0);
    rownorm<<<NGOALS, 256, 0, stream>>>(xcat, out);
}

// Round 2
// 2332.647 us; speedup vs baseline: 12.5776x; 12.5776x over previous
//
#include <hip/hip_runtime.h>
#include <hip/hip_bf16.h>

#define HH 500
#define G4 2000
#define NSEQ 2304
#define NGOALS 256
#define NHYPS 2048
#define LSEQ 128
#define NVOCAB 1000
#define NEG_SLOPE 0.01f

typedef __attribute__((ext_vector_type(4))) float f32x4;
typedef __attribute__((ext_vector_type(8))) short short8;

__device__ __forceinline__ float sigm(float x) { return 1.0f / (1.0f + expf(-x)); }

__device__ __forceinline__ void gload_lds16(const void* g, void* l) {
    __builtin_amdgcn_global_load_lds(
        (const __attribute__((address_space(1))) unsigned int*)g,
        (__attribute__((address_space(3))) unsigned int*)l, 16, 0, 0);
}

// Generic fp32 C[M,N] = act(A[M,K] @ B[N,K]^T + bias[n] (+bias2[n]))
__global__ void gemm_at_bt(const float* __restrict__ A, const float* __restrict__ B,
                           const float* __restrict__ bias, const float* __restrict__ bias2,
                           float* __restrict__ C, int M, int N, int K, int act)
{
    __shared__ float as[32][17];
    __shared__ float bs[32][17];
    int tid = threadIdx.x;
    int tx = tid & 15, ty = tid >> 4;
    int m0 = blockIdx.y * 32, n0 = blockIdx.x * 32;
    float acc[2][2] = {};
    for (int k0 = 0; k0 < K; k0 += 16) {
        #pragma unroll
        for (int i = 0; i < 2; ++i) {
            int idx = i * 256 + tid;
            int r = idx >> 4, k = idx & 15;
            int gm = m0 + r, gk = k0 + k;
            as[r][k] = (gm < M && gk < K) ? A[gm * K + gk] : 0.0f;
            int gn = n0 + r;
            bs[r][k] = (gn < N && gk < K) ? B[gn * K + gk] : 0.0f;
        }
        __syncthreads();
        #pragma unroll
        for (int kk = 0; kk < 16; ++kk) {
            float a0 = as[ty][kk], a1 = as[ty + 16][kk];
            float b0 = bs[tx][kk], b1 = bs[tx + 16][kk];
            acc[0][0] += a0 * b0; acc[0][1] += a0 * b1;
            acc[1][0] += a1 * b0; acc[1][1] += a1 * b1;
        }
        __syncthreads();
    }
    #pragma unroll
    for (int i = 0; i < 2; ++i) {
        int m = m0 + ty + i * 16;
        if (m >= M) continue;
        #pragma unroll
        for (int j = 0; j < 2; ++j) {
            int n = n0 + tx + j * 16;
            if (n >= N) continue;
            float v = acc[i][j];
            if (bias)  v += bias[n];
            if (bias2) v += bias2[n];
            if (act == 1) v = (v >= 0.0f) ? v : NEG_SLOPE * v;
            C[m * N + n] = v;
        }
    }
}

// Whh fp32 [2000][500] -> bf16 Wb[4][512][512] (gate, u, k), zero-padded
__global__ void conv_whh(const float* __restrict__ Whh, __hip_bfloat16* __restrict__ Wb)
{
    int idx = blockIdx.x * 256 + threadIdx.x;
    if (idx >= 4 * 512 * 512) return;
    int k = idx & 511, u = (idx >> 9) & 511, g = idx >> 18;
    float v = (u < HH && k < HH) ? Whh[(g * HH + u) * HH + k] : 0.0f;
    Wb[idx] = __float2bfloat16(v);
}

// One LSTM step: gates = T[tok] + h @ Whh^T via bf16 MFMA, fused pointwise.
// Block: 256 thr (4 waves), tile n32 x u32, all 4 gates.
// Wave w: n-sub (w>>1)*16, u-sub (w&1)*16; acc[g] = 16x16 frag.
__global__ __launch_bounds__(256) void lstm_step_mfma(
    const float* __restrict__ T,
    const int* __restrict__ goals, const int* __restrict__ hyps,
    const __hip_bfloat16* __restrict__ Wb,
    const __hip_bfloat16* __restrict__ hin,
    __hip_bfloat16* __restrict__ hout,
    float* __restrict__ c, int t)
{
    __shared__ char lds[20480];          // As [32][128B] @0, Bs [128][128B] @4096
    char* As = lds;
    char* Bs = lds + 4096;
    int tid = threadIdx.x, w = tid >> 6, lane = tid & 63;
    int n0 = blockIdx.y * 32, u0 = blockIdx.x * 32;
    f32x4 acc[4] = {};

    int lrow = lane >> 3;                // 0..7 row-in-group for staging
    int cblk = (lane & 7) ^ lrow;        // pre-swizzled global col-block
    const short* hin_s = (const short*)hin;
    const short* wb_s  = (const short*)Wb;

    int nsub = (w >> 1) * 16, usub = (w & 1) * 16;
    int arow = nsub + (lane & 15);
    int r7 = lane & 7;                   // = row&7 for both A and B frag rows

    for (int k0 = 0; k0 < 512; k0 += 64) {
        // stage A: wave w covers tile rows w*8 .. w*8+7 (LDS linear, src swizzled)
        gload_lds16(hin_s + (size_t)(n0 + w * 8 + lrow) * 512 + k0 + cblk * 8,
                    As + w * 1024);
        // stage B: 128 rows (gate*32 + u), 4 issues per wave
        #pragma unroll
        for (int i = 0; i < 4; ++i) {
            int r = (i * 4 + w) * 8 + lrow;          // 0..127
            int g = r >> 5, u = u0 + (r & 31);
            gload_lds16(wb_s + (size_t)(g * 512 + u) * 512 + k0 + cblk * 8,
                        Bs + (i * 4 + w) * 1024);
        }
        __syncthreads();
        #pragma unroll
        for (int ks = 0; ks < 2; ++ks) {
            int blk = (ks * 4 + (lane >> 4)) ^ r7;
            short8 a = *(const short8*)(As + arow * 128 + blk * 16);
            #pragma unroll
            for (int g = 0; g < 4; ++g) {
                int br = g * 32 + usub + (lane & 15);
                short8 b = *(const short8*)(Bs + br * 128 + blk * 16);
                acc[g] = __builtin_amdgcn_mfma_f32_16x16x32_bf16(a, b, acc[g], 0, 0, 0);
            }
        }
        __syncthreads();
    }

    // epilogue: lane holds col u = u0+usub+(lane&15); rows (lane>>4)*4 + r
    int u = u0 + usub + (lane & 15);
    if (u < HH) {
        #pragma unroll
        for (int r = 0; r < 4; ++r) {
            int n = n0 + nsub + (lane >> 4) * 4 + r;
            int tok = (n < NGOALS) ? goals[n * LSEQ + t] : hyps[(n - NGOALS) * LSEQ + t];
            const float* Trow = T + (size_t)tok * G4;
            float gi = acc[0][r] + Trow[u];
            float gf = acc[1][r] + Trow[HH + u];
            float gg = acc[2][r] + Trow[2 * HH + u];
            float go = acc[3][r] + Trow[3 * HH + u];
            float si = sigm(gi), sf = sigm(gf), so = sigm(go);
            float cv = c[(size_t)n * 512 + u];
            cv = sf * cv + si * tanhf(gg);
            c[(size_t)n * 512 + u] = cv;
            hout[(size_t)n * 512 + u] = __float2bfloat16(so * tanhf(cv));
        }
    }
}

__global__ void segsum_bf(const __hip_bfloat16* __restrict__ hfin,
                          const int* __restrict__ segid, float* __restrict__ hyp_sum)
{
    int row = blockIdx.y;
    int u = blockIdx.x * 256 + threadIdx.x;
    if (u >= HH) return;
    int b = segid[row];
    atomicAdd(&hyp_sum[b * HH + u],
              __bfloat162float(hfin[(size_t)(NGOALS + row) * 512 + u]));
}

__global__ void concat_bf(const __hip_bfloat16* __restrict__ hfin,
                          const float* __restrict__ hyp_sum, float* __restrict__ xcat)
{
    int r = blockIdx.y;
    int k = blockIdx.x * 256 + threadIdx.x;
    if (k >= 2 * HH) return;
    xcat[r * 2 * HH + k] = (k < HH) ? __bfloat162float(hfin[(size_t)r * 512 + k])
                                    : hyp_sum[r * HH + (k - HH)];
}

__global__ void rownorm(const float* __restrict__ X, float* __restrict__ out)
{
    __shared__ float red[256];
    int r = blockIdx.x;
    int tid = threadIdx.x;
    float v0 = (tid < HH) ? X[r * HH + tid] : 0.0f;
    float v1 = (tid + 256 < HH) ? X[r * HH + tid + 256] : 0.0f;
    red[tid] = v0 * v0 + v1 * v1;
    __syncthreads();
    for (int st = 128; st > 0; st >>= 1) {
        if (tid < st) red[tid] += red[tid + st];
        __syncthreads();
    }
    float nrm = fmaxf(sqrtf(red[0]), 1e-12f);
    if (tid < HH) out[r * HH + tid] = v0 / nrm;
    if (tid + 256 < HH) out[r * HH + tid + 256] = v1 / nrm;
}

extern "C" void kernel_launch(void* const* d_in, const int* in_sizes, int n_in,
                              void* d_out, int out_size, void* d_ws, size_t ws_size,
                              hipStream_t stream)
{
    const int*   goals = (const int*)d_in[0];
    const int*   hyps  = (const int*)d_in[1];
    const int*   segid = (const int*)d_in[2];
    const float* emb   = (const float*)d_in[3];
    const float* Wih   = (const float*)d_in[4];
    const float* Whh   = (const float*)d_in[5];
    const float* bih   = (const float*)d_in[6];
    const float* bhh   = (const float*)d_in[7];
    const float* W1    = (const float*)d_in[8];
    const float* b1    = (const float*)d_in[9];
    const float* W2    = (const float*)d_in[10];
    const float* b2    = (const float*)d_in[11];
    const float* Wf    = (const float*)d_in[12];
    const float* bf    = (const float*)d_in[13];
    float* out = (float*)d_out;

    char* base = (char*)d_ws;
    float*          T    = (float*)(base + 0);                  // 8,000,000 B
    __hip_bfloat16* Wb   = (__hip_bfloat16*)(base + 8000000);   // 2,097,152 B
    __hip_bfloat16* hb0  = (__hip_bfloat16*)(base + 10097152);  // 2,359,296 B
    __hip_bfloat16* hb1  = (__hip_bfloat16*)(base + 12456448);  // 2,359,296 B
    float*          c    = (float*)(base + 14815744);           // 4,718,592 B
    float*          hsum = (float*)(base + 19534336);           //   512,000 B
    float*          xcat = (float*)(base + 20046336);           // 1,024,000 B
    float*          x1   = (float*)(base + 21070336);           //   512,000 B
    float*          x2   = (float*)(base + 21582336);           //   512,000 B

    // Token-gate table (fp32): T = emb @ Wih^T + bih + bhh   [1000 x 2000]
    gemm_at_bt<<<dim3((G4 + 31) / 32, (NVOCAB + 31) / 32), 256, 0, stream>>>(
        emb, Wih, bih, bhh, T, NVOCAB, G4, HH, 0);
    // Whh -> bf16 padded [4][512][512]
    conv_whh<<<4096, 256, 0, stream>>>(Whh, Wb);

    hipMemsetAsync(hb0,  0, 2359296, stream);
    hipMemsetAsync(hb1,  0, 2359296, stream);
    hipMemsetAsync(c,    0, 4718592, stream);
    hipMemsetAsync(hsum, 0,  512000, stream);

    __hip_bfloat16* hb[2] = { hb0, hb1 };
    for (int t = 0; t < LSEQ; ++t) {
        lstm_step_mfma<<<dim3(16, NSEQ / 32), 256, 0, stream>>>(
            T, goals, hyps, Wb, hb[t & 1], hb[(t + 1) & 1], c, t);
    }
    __hip_bfloat16* hfin = hb0;   // after 128 steps

    segsum_bf<<<dim3(2, NHYPS), 256, 0, stream>>>(hfin, segid, hsum);
    concat_bf<<<dim3(4, NGOALS), 256, 0, stream>>>(hfin, hsum, xcat);

    gemm_at_bt<<<dim3(16, 8), 256, 0, stream>>>(xcat, W1, b1, nullptr, x1, NGOALS, HH, 2 * HH, 1);
    gemm_at_bt<<<dim3(16, 8), 256, 0, stream>>>(x1,   W2, b2, nullptr, x2, NGOALS, HH, HH, 1);
    gemm_at_bt<<<dim3(16, 8), 256, 0, stream>>>(x2,   Wf, bf, nullptr, xcat, NGOALS, HH, HH, 0);
    rownorm<<<NGOALS, 256, 0, stream>>>(xcat, out);
}